// Round 3
// baseline (304.573 us; speedup 1.0000x reference)
//
#include <hip/hip_runtime.h>
#include <hip/hip_bf16.h>
#include <stdint.h>

#define B_ 2
#define N_ 4096
#define C_ 512
#define H_ 8
#define D_ 64
#define M_ (B_*N_)     // 8192
#define K3_ (3*C_)     // 1536

typedef __attribute__((ext_vector_type(8)))  short short8;
typedef __attribute__((ext_vector_type(4)))  float f32x4;
typedef __attribute__((ext_vector_type(16))) float f32x16;

// ---------- helpers ----------
static __device__ __forceinline__ unsigned short f2bf(float f) {
  union { float f; unsigned u; } cv; cv.f = f;
  unsigned r = cv.u + 0x7fffu + ((cv.u >> 16) & 1u);   // RNE
  return (unsigned short)(r >> 16);
}
static __device__ __forceinline__ float bf2f(short x) {
  union { unsigned u; float f; } cv;
  cv.u = ((unsigned)(unsigned short)x) << 16;
  return cv.f;
}
static __device__ __forceinline__ float fexp2(float x) {
#if __has_builtin(__builtin_amdgcn_exp2f)
  return __builtin_amdgcn_exp2f(x);
#else
  return exp2f(x);
#endif
}
static __device__ __forceinline__ unsigned cvt_pk_bf16(float a, float b) {
  unsigned r;
  asm("v_cvt_pk_bf16_f32 %0, %1, %2" : "=v"(r) : "v"(a), "v"(b));
  return r;   // lo = bf16(a), hi = bf16(b)
}
static __device__ __forceinline__ f32x16 zero16() {
  f32x16 z;
#pragma unroll
  for (int i = 0; i < 16; i++) z[i] = 0.f;
  return z;
}

// ---------- f32 -> bf16 cast ----------
__global__ void cast_f2b(const float* __restrict__ in, short* __restrict__ out, int n4) {
  int i = blockIdx.x * blockDim.x + threadIdx.x;
  if (i >= n4) return;
  float4 v = ((const float4*)in)[i];
  short4 o;
  o.x = (short)f2bf(v.x); o.y = (short)f2bf(v.y);
  o.z = (short)f2bf(v.z); o.w = (short)f2bf(v.w);
  ((short4*)out)[i] = o;
}

// ---------- RoPE cos/sin table ----------
__global__ void rope_table(float2* __restrict__ tab) {
  int i = blockIdx.x * blockDim.x + threadIdx.x;   // 4096*32
  if (i >= N_ * 32) return;
  int p = i & 31, n = i >> 5;
  float freq = exp2f(-((float)(2 * p) / 64.0f) * 13.287712379549449f);
  float ang = (float)n * freq;
  float s, c;
  sincosf(ang, &s, &c);
  float2 r; r.x = c; r.y = s;
  tab[i] = r;
}

// ---------- RoPE apply ----------
__global__ void rope_apply(const short* __restrict__ qkvb, const float2* __restrict__ tab,
                           short* __restrict__ Qr, short* __restrict__ Kr) {
  int idx = blockIdx.x * blockDim.x + threadIdx.x;   // 2*8192*64
  if (idx >= 2 * M_ * 64) return;
  int d8 = idx & 7;
  int h  = (idx >> 3) & 7;
  int m  = (idx >> 6) & (M_ - 1);
  int tk = idx >> 19;                 // 0 = q, 1 = k
  int n = m & (N_ - 1), b = m >> 12;
  short8 v = *(const short8*)(qkvb + (size_t)m * K3_ + tk * C_ + h * D_ + d8 * 8);
  const float2* tp = tab + n * 32 + d8 * 4;
  float sc = (tk == 0) ? 0.18033688011112042f : 1.0f;  // SCALE * log2(e) on Q
  short8 w;
#pragma unroll
  for (int j = 0; j < 4; j++) {
    float e = bf2f(v[2 * j]), o = bf2f(v[2 * j + 1]);
    float2 cs = tp[j];
    float e2 = (e * cs.x - o * cs.y) * sc;
    float o2 = (e * cs.y + o * cs.x) * sc;
    w[2 * j] = (short)f2bf(e2);
    w[2 * j + 1] = (short)f2bf(o2);
  }
  short* dst = (tk ? Kr : Qr) + ((size_t)((b * H_ + h) * N_ + n)) * D_ + d8 * 8;
  *(short8*)dst = w;
}

// ---------- V transpose: qkvb V-part -> Vt[bh][d][n] ----------
__global__ void vtrans(const short* __restrict__ qkvb, short* __restrict__ Vt) {
  __shared__ short tile[64][72];
  int bh = blockIdx.x;        // 16
  int nt = blockIdx.y;        // 64
  int b = bh >> 3, h = bh & 7;
  int t = threadIdx.x;
  int n0 = nt * 64;
  const short* src = qkvb + ((size_t)(b * N_ + n0)) * K3_ + 2 * C_ + h * D_;
#pragma unroll
  for (int it = 0; it < 2; it++) {
    int nn = it * 32 + (t >> 3), c8 = t & 7;
    short8 v = *(const short8*)(src + (size_t)nn * K3_ + c8 * 8);
    *(short8*)&tile[nn][c8 * 8] = v;
  }
  __syncthreads();
#pragma unroll
  for (int it = 0; it < 2; it++) {
    int d = it * 32 + (t >> 3), n8 = t & 7;
    short8 w;
#pragma unroll
    for (int j = 0; j < 8; j++) w[j] = tile[n8 * 8 + j][d];
    *(short8*)(Vt + ((size_t)(bh * D_ + d)) * N_ + n0 + n8 * 8) = w;
  }
}

// ---------- GEMM ----------
template<int OUTF32>
__global__ __launch_bounds__(256) void gemm_bt(const short* __restrict__ A, const short* __restrict__ Bw,
                                               const float* __restrict__ bias, void* __restrict__ Cout,
                                               int M, int Nout, int K) {
  __shared__ short As[128 * 40];
  __shared__ short Bs[128 * 40];
  int t = threadIdx.x, lane = t & 63, w = t >> 6, wr = w >> 1, wc = w & 1;
  int tM = blockIdx.x * 128, tN = blockIdx.y * 128;
  int lrow = lane & 15, lhi = lane >> 4;
  f32x4 acc[4][4];
#pragma unroll
  for (int fm = 0; fm < 4; fm++)
#pragma unroll
    for (int fn = 0; fn < 4; fn++)
#pragma unroll
      for (int r = 0; r < 4; r++) acc[fm][fn][r] = 0.f;

  for (int k0 = 0; k0 < K; k0 += 32) {
#pragma unroll
    for (int i = 0; i < 2; i++) {
      int c = t + 256 * i, r = c >> 2, q = c & 3;
      *(uint4*)(As + r * 40 + q * 8) = *(const uint4*)(A  + (size_t)(tM + r) * K + k0 + q * 8);
      *(uint4*)(Bs + r * 40 + q * 8) = *(const uint4*)(Bw + (size_t)(tN + r) * K + k0 + q * 8);
    }
    __syncthreads();
    short8 af[4], bfr[4];
#pragma unroll
    for (int f = 0; f < 4; f++) {
      af[f]  = *(const short8*)(As + (wr * 64 + f * 16 + lrow) * 40 + lhi * 8);
      bfr[f] = *(const short8*)(Bs + (wc * 64 + f * 16 + lrow) * 40 + lhi * 8);
    }
#pragma unroll
    for (int fm = 0; fm < 4; fm++)
#pragma unroll
      for (int fn = 0; fn < 4; fn++)
        acc[fm][fn] = __builtin_amdgcn_mfma_f32_16x16x32_bf16(af[fm], bfr[fn], acc[fm][fn], 0, 0, 0);
    __syncthreads();
  }

#pragma unroll
  for (int fn = 0; fn < 4; fn++) {
    int col = tN + wc * 64 + fn * 16 + lrow;
    float bv = bias[col];
#pragma unroll
    for (int fm = 0; fm < 4; fm++) {
      int row0 = tM + wr * 64 + fm * 16 + lhi * 4;
#pragma unroll
      for (int r = 0; r < 4; r++) {
        float v = acc[fm][fn][r] + bv;
        if (OUTF32) ((float*)Cout)[(size_t)(row0 + r) * Nout + col] = v;
        else        ((short*)Cout)[(size_t)(row0 + r) * Nout + col] = (short)f2bf(v);
      }
    }
  }
}

// ---------- Flash attention with 2-way KV split ----------
// grid (16 heads, 32 q-blocks, 2 kv-chunks), 256 thr = 4 waves, each wave 32 q rows
__global__ __launch_bounds__(256, 4) void attn(const short* __restrict__ Qr, const short* __restrict__ Kr,
                                               const short* __restrict__ Vt,
                                               float* __restrict__ Op, float* __restrict__ lp) {
  int bh = blockIdx.x;
  int ch = blockIdx.z;
  int wv = threadIdx.x >> 6, lane = threadIdx.x & 63;
  int c = lane & 31, hi = lane >> 5;
  int q0 = blockIdx.y * 128 + wv * 32;
  const short* Qh = Qr + (size_t)bh * N_ * D_;
  const short* Kh = Kr + (size_t)bh * N_ * D_;
  const short* Vh = Vt + (size_t)bh * D_ * N_;
  int kstart = ch * (N_ / 2), kend = kstart + (N_ / 2);

  short8 qf[4];
  {
    const short* qrow = Qh + (size_t)(q0 + c) * D_ + hi * 8;
#pragma unroll
    for (int f = 0; f < 4; f++) qf[f] = *(const short8*)(qrow + f * 16);
  }
  f32x16 o0 = zero16(), o1 = zero16();
  float lsum = 0.f;

  short8 kf[4];
  {
    const short* krow = Kh + (size_t)(kstart + c) * D_ + hi * 8;
#pragma unroll
    for (int f = 0; f < 4; f++) kf[f] = *(const short8*)(krow + f * 16);
  }

  for (int kb = kstart; kb < kend; kb += 32) {
    // V B-frags (issued early; consumed after softmax)
    short8 vf00 = *(const short8*)(Vh + (size_t)(c)      * N_ + kb +      hi * 8);
    short8 vf10 = *(const short8*)(Vh + (size_t)(c)      * N_ + kb + 16 + hi * 8);
    short8 vf01 = *(const short8*)(Vh + (size_t)(32 + c) * N_ + kb +      hi * 8);
    short8 vf11 = *(const short8*)(Vh + (size_t)(32 + c) * N_ + kb + 16 + hi * 8);

    f32x16 st = zero16();
#pragma unroll
    for (int f = 0; f < 4; f++)
      st = __builtin_amdgcn_mfma_f32_32x32x16_bf16(kf[f], qf[f], st, 0, 0, 0);

    // prefetch next K tile into regs (wraps harmlessly on last iter)
    int kbn = (kb + 32 < kend) ? kb + 32 : kstart;
    short8 kfn[4];
    {
      const short* krow = Kh + (size_t)(kbn + c) * D_ + hi * 8;
#pragma unroll
      for (int f = 0; f < 4; f++) kfn[f] = *(const short8*)(krow + f * 16);
    }

    // softmax numerators: exp2 then pack to bf16x2 via v_cvt_pk
    float ls = 0.f;
    unsigned cpk[8];
#pragma unroll
    for (int q2 = 0; q2 < 4; q2++) {
      float e0 = fexp2(st[4 * q2]),     e1 = fexp2(st[4 * q2 + 1]);
      float e2 = fexp2(st[4 * q2 + 2]), e3 = fexp2(st[4 * q2 + 3]);
      ls += (e0 + e1) + (e2 + e3);
      cpk[2 * q2]     = cvt_pk_bf16(e0, e1);
      cpk[2 * q2 + 1] = cvt_pk_bf16(e2, e3);
    }
    lsum += ls;

    unsigned pc[8];
#pragma unroll
    for (int i = 0; i < 8; i++) pc[i] = (unsigned)__shfl_xor((int)cpk[i], 32);

    union { unsigned u[4]; short8 s; } u0, u1;
    if (hi == 0) {
      u0.u[0] = cpk[0]; u0.u[1] = cpk[1]; u0.u[2] = pc[0]; u0.u[3] = pc[1];
      u1.u[0] = cpk[4]; u1.u[1] = cpk[5]; u1.u[2] = pc[4]; u1.u[3] = pc[5];
    } else {
      u0.u[0] = pc[2]; u0.u[1] = pc[3]; u0.u[2] = cpk[2]; u0.u[3] = cpk[3];
      u1.u[0] = pc[6]; u1.u[1] = pc[7]; u1.u[2] = cpk[6]; u1.u[3] = cpk[7];
    }
    o0 = __builtin_amdgcn_mfma_f32_32x32x16_bf16(u0.s, vf00, o0, 0, 0, 0);
    o0 = __builtin_amdgcn_mfma_f32_32x32x16_bf16(u1.s, vf10, o0, 0, 0, 0);
    o1 = __builtin_amdgcn_mfma_f32_32x32x16_bf16(u0.s, vf01, o1, 0, 0, 0);
    o1 = __builtin_amdgcn_mfma_f32_32x32x16_bf16(u1.s, vf11, o1, 0, 0, 0);

#pragma unroll
    for (int f = 0; f < 4; f++) kf[f] = kfn[f];
  }

  float lt = lsum + __shfl_xor(lsum, 32);
  if (hi == 0) lp[((size_t)ch * 16 + bh) * N_ + q0 + c] = lt;
  float* obase = Op + ((size_t)ch * 16 + bh) * N_ * D_;
#pragma unroll
  for (int r = 0; r < 16; r++) {
    int ql = (r & 3) + 8 * (r >> 2) + 4 * hi;
    int n = q0 + ql;
    obase[(size_t)n * D_ + c]      = o0[r];
    obase[(size_t)n * D_ + 32 + c] = o1[r];
  }
}

// ---------- combine partials -> AO bf16 ----------
__global__ void combine(const float* __restrict__ Op, const float* __restrict__ lp,
                        short* __restrict__ AO) {
  int i = blockIdx.x * blockDim.x + threadIdx.x;   // 16*4096*16
  if (i >= 16 * N_ * 16) return;
  int d4 = i & 15, q = (i >> 4) & (N_ - 1), bh = i >> 16;
  size_t base = ((size_t)bh * N_ + q) * D_ + d4 * 4;
  const size_t chstride = (size_t)16 * N_ * D_;
  float4 a = *(const float4*)(Op + base);
  float4 b = *(const float4*)(Op + base + chstride);
  float l = lp[(size_t)bh * N_ + q] + lp[(size_t)16 * N_ + (size_t)bh * N_ + q];
  float inv = 1.0f / l;
  int bb = bh >> 3, h = bh & 7;
  short4 o;
  o.x = (short)f2bf((a.x + b.x) * inv);
  o.y = (short)f2bf((a.y + b.y) * inv);
  o.z = (short)f2bf((a.z + b.z) * inv);
  o.w = (short)f2bf((a.w + b.w) * inv);
  *(short4*)(AO + ((size_t)(bb * N_ + q)) * C_ + h * D_ + d4 * 4) = o;
}

// ---------- launch ----------
extern "C" void kernel_launch(void* const* d_in, const int* in_sizes, int n_in,
                              void* d_out, int out_size, void* d_ws, size_t ws_size,
                              hipStream_t stream) {
  const float* x     = (const float*)d_in[0];
  const float* Wqkv  = (const float*)d_in[1];
  const float* bqkv  = (const float*)d_in[2];
  const float* Wproj = (const float*)d_in[3];
  const float* bproj = (const float*)d_in[4];
  float* out = (float*)d_out;
  char* ws = (char*)d_ws;

  // persistent region
  const size_t off_wprjb = 0;          // 524,288
  const size_t off_tab   = 524288;     // 1,048,576
  const size_t off_q     = 1572864;    // 8,388,608
  const size_t off_k     = 9961472;    // 8,388,608
  const size_t off_vt    = 18350080;   // 8,388,608
  const size_t off_ao    = 26738688;   // 8,388,608 -> ends 35,127,296
  // phase-1 transient (aliased below by partials)
  const size_t off_xb    = 35127296;   // 8,388,608
  const size_t off_wqkvb = 43515904;   // 1,572,864
  const size_t off_qkvb  = 45088768;   // 25,165,824 -> ends 70,254,592
  // attn-phase partials (alias xb/wqkvb/qkvb)
  const size_t off_op    = 35127296;   // 2*16*4096*64*4 = 33,554,432
  const size_t off_l     = 68681728;   // 2*16*4096*4    =    524,288 -> ends 69,206,016
  if (ws_size < 70254592) return;

  short* xb    = (short*)(ws + off_xb);
  short* wqkvb = (short*)(ws + off_wqkvb);
  short* wprjb = (short*)(ws + off_wprjb);
  short* qkvb  = (short*)(ws + off_qkvb);
  short* Qrp   = (short*)(ws + off_q);
  short* Krp   = (short*)(ws + off_k);
  short* Vtp   = (short*)(ws + off_vt);
  short* AOp   = (short*)(ws + off_ao);
  float2* tab  = (float2*)(ws + off_tab);
  float* Opp   = (float*)(ws + off_op);
  float* lpp   = (float*)(ws + off_l);

  cast_f2b<<<dim3(4096), dim3(256), 0, stream>>>(x,     xb,    M_ * C_ / 4);
  cast_f2b<<<dim3(768),  dim3(256), 0, stream>>>(Wqkv,  wqkvb, K3_ * C_ / 4);
  cast_f2b<<<dim3(256),  dim3(256), 0, stream>>>(Wproj, wprjb, C_ * C_ / 4);
  rope_table<<<dim3(512), dim3(256), 0, stream>>>(tab);

  gemm_bt<0><<<dim3(64, 12), dim3(256), 0, stream>>>(xb, wqkvb, bqkv, qkvb, M_, K3_, C_);

  rope_apply<<<dim3(4096), dim3(256), 0, stream>>>(qkvb, tab, Qrp, Krp);
  vtrans<<<dim3(16, 64), dim3(256), 0, stream>>>(qkvb, Vtp);

  attn<<<dim3(16, 32, 2), dim3(256), 0, stream>>>(Qrp, Krp, Vtp, Opp, lpp);
  combine<<<dim3(4096), dim3(256), 0, stream>>>(Opp, lpp, AOp);

  gemm_bt<1><<<dim3(64, 4), dim3(256), 0, stream>>>(AOp, wprjb, bproj, (void*)out, M_, C_, C_);
}

// Round 4
// 160.970 us; speedup vs baseline: 1.8921x; 1.8921x over previous
//
#include <hip/hip_runtime.h>
#include <hip/hip_bf16.h>
#include <stdint.h>

#define B_ 2
#define N_ 4096
#define C_ 512
#define H_ 8
#define D_ 64
#define M_ (B_*N_)     // 8192
#define K3_ (3*C_)     // 1536

typedef __attribute__((ext_vector_type(8)))  short short8;
typedef __attribute__((ext_vector_type(4)))  float f32x4;
typedef __attribute__((ext_vector_type(16))) float f32x16;

// ---------- helpers ----------
static __device__ __forceinline__ unsigned short f2bf(float f) {
  union { float f; unsigned u; } cv; cv.f = f;
  unsigned r = cv.u + 0x7fffu + ((cv.u >> 16) & 1u);   // RNE
  return (unsigned short)(r >> 16);
}
static __device__ __forceinline__ float bf2f(short x) {
  union { unsigned u; float f; } cv;
  cv.u = ((unsigned)(unsigned short)x) << 16;
  return cv.f;
}
static __device__ __forceinline__ float fexp2(float x) {
#if __has_builtin(__builtin_amdgcn_exp2f)
  return __builtin_amdgcn_exp2f(x);
#else
  return exp2f(x);
#endif
}
static __device__ __forceinline__ unsigned cvt_pk_bf16(float a, float b) {
  unsigned r;
  asm("v_cvt_pk_bf16_f32 %0, %1, %2" : "=v"(r) : "v"(a), "v"(b));
  return r;   // lo = bf16(a), hi = bf16(b)
}
static __device__ __forceinline__ f32x16 zero16() {
  f32x16 z;
#pragma unroll
  for (int i = 0; i < 16; i++) z[i] = 0.f;
  return z;
}

// ---------- f32 -> bf16 cast ----------
__global__ void cast_f2b(const float* __restrict__ in, short* __restrict__ out, int n4) {
  int i = blockIdx.x * blockDim.x + threadIdx.x;
  if (i >= n4) return;
  float4 v = ((const float4*)in)[i];
  short4 o;
  o.x = (short)f2bf(v.x); o.y = (short)f2bf(v.y);
  o.z = (short)f2bf(v.z); o.w = (short)f2bf(v.w);
  ((short4*)out)[i] = o;
}

// ---------- RoPE cos/sin table ----------
__global__ void rope_table(float2* __restrict__ tab) {
  int i = blockIdx.x * blockDim.x + threadIdx.x;   // 4096*32
  if (i >= N_ * 32) return;
  int p = i & 31, n = i >> 5;
  float freq = exp2f(-((float)(2 * p) / 64.0f) * 13.287712379549449f);
  float ang = (float)n * freq;
  float s, c;
  sincosf(ang, &s, &c);
  float2 r; r.x = c; r.y = s;
  tab[i] = r;
}

// ---------- RoPE apply -> fragment-ready Qf/Kf ----------
// Layout: Qf[(( (b*8+h)*128 + nblk )*4 + f)*512 + lane*8 + j] = Q[b,h, nblk*32+ (lane&31), f*16 + (lane>>5)*8 + j]
__global__ void rope_apply(const short* __restrict__ qkvb, const float2* __restrict__ tab,
                           short* __restrict__ Qf, short* __restrict__ Kf) {
  int idx = blockIdx.x * blockDim.x + threadIdx.x;   // 2^20
  if (idx >= 2 * M_ * 64) return;
  int lane  = idx & 63;
  int f     = (idx >> 6) & 3;
  int nblk  = (idx >> 8) & 127;
  int h     = (idx >> 15) & 7;
  int b     = (idx >> 18) & 1;
  int tk    = idx >> 19;               // 0 = q, 1 = k
  int c = lane & 31, hi = lane >> 5;
  int n = nblk * 32 + c;
  int d0 = f * 16 + hi * 8;
  short8 v = *(const short8*)(qkvb + (size_t)(b * N_ + n) * K3_ + tk * C_ + h * D_ + d0);
  const float2* tp = tab + n * 32 + (d0 >> 1);
  float sc = (tk == 0) ? 0.18033688011112042f : 1.0f;  // SCALE * log2(e) on Q
  short8 w;
#pragma unroll
  for (int j = 0; j < 4; j++) {
    float e = bf2f(v[2 * j]), o = bf2f(v[2 * j + 1]);
    float2 cs = tp[j];
    float e2 = (e * cs.x - o * cs.y) * sc;
    float o2 = (e * cs.y + o * cs.x) * sc;
    w[2 * j] = (short)f2bf(e2);
    w[2 * j + 1] = (short)f2bf(o2);
  }
  short* dst = (tk ? Kf : Qf) + (((size_t)((b * H_ + h) * 128 + nblk) * 4 + f) * 512) + lane * 8;
  *(short8*)dst = w;
}

// ---------- V -> fragment-ready Vf ----------
// Vf[((bh*128 + kblk)*4 + frag)*512 + lane*8 + j] = V[bh, n=kblk*32 + (frag&1)*16 + (lane>>5)*8 + j, d=(frag>>1)*32 + (lane&31)]
__global__ void vtrans(const short* __restrict__ qkvb, short* __restrict__ Vf) {
  __shared__ short tile[32][72];
  int bh = blockIdx.x;        // 16
  int kblk = blockIdx.y;      // 128
  int b = bh >> 3, h = bh & 7;
  int t = threadIdx.x;
  int n0 = kblk * 32;
  {
    int row = t >> 3, c8 = t & 7;
    short8 v = *(const short8*)(qkvb + (size_t)(b * N_ + n0 + row) * K3_ + 2 * C_ + h * D_ + c8 * 8);
    *(short8*)&tile[row][c8 * 8] = v;
  }
  __syncthreads();
  {
    int frag = t >> 6, lane = t & 63;
    int hi = lane >> 5, c = lane & 31;
    int g = frag & 1, dblk = frag >> 1;
    short8 w;
#pragma unroll
    for (int j = 0; j < 8; j++) w[j] = tile[g * 16 + hi * 8 + j][dblk * 32 + c];
    *(short8*)(Vf + ((size_t)(bh * 128 + kblk) * 4 + frag) * 512 + lane * 8) = w;
  }
}

// ---------- GEMM ----------
template<int OUTF32>
__global__ __launch_bounds__(256) void gemm_bt(const short* __restrict__ A, const short* __restrict__ Bw,
                                               const float* __restrict__ bias, void* __restrict__ Cout,
                                               int M, int Nout, int K) {
  __shared__ short As[128 * 40];
  __shared__ short Bs[128 * 40];
  int t = threadIdx.x, lane = t & 63, w = t >> 6, wr = w >> 1, wc = w & 1;
  int tM = blockIdx.x * 128, tN = blockIdx.y * 128;
  int lrow = lane & 15, lhi = lane >> 4;
  f32x4 acc[4][4];
#pragma unroll
  for (int fm = 0; fm < 4; fm++)
#pragma unroll
    for (int fn = 0; fn < 4; fn++)
#pragma unroll
      for (int r = 0; r < 4; r++) acc[fm][fn][r] = 0.f;

  for (int k0 = 0; k0 < K; k0 += 32) {
#pragma unroll
    for (int i = 0; i < 2; i++) {
      int c = t + 256 * i, r = c >> 2, q = c & 3;
      *(uint4*)(As + r * 40 + q * 8) = *(const uint4*)(A  + (size_t)(tM + r) * K + k0 + q * 8);
      *(uint4*)(Bs + r * 40 + q * 8) = *(const uint4*)(Bw + (size_t)(tN + r) * K + k0 + q * 8);
    }
    __syncthreads();
    short8 af[4], bfr[4];
#pragma unroll
    for (int f = 0; f < 4; f++) {
      af[f]  = *(const short8*)(As + (wr * 64 + f * 16 + lrow) * 40 + lhi * 8);
      bfr[f] = *(const short8*)(Bs + (wc * 64 + f * 16 + lrow) * 40 + lhi * 8);
    }
#pragma unroll
    for (int fm = 0; fm < 4; fm++)
#pragma unroll
      for (int fn = 0; fn < 4; fn++)
        acc[fm][fn] = __builtin_amdgcn_mfma_f32_16x16x32_bf16(af[fm], bfr[fn], acc[fm][fn], 0, 0, 0);
    __syncthreads();
  }

#pragma unroll
  for (int fn = 0; fn < 4; fn++) {
    int col = tN + wc * 64 + fn * 16 + lrow;
    float bv = bias[col];
#pragma unroll
    for (int fm = 0; fm < 4; fm++) {
      int row0 = tM + wr * 64 + fm * 16 + lhi * 4;
#pragma unroll
      for (int r = 0; r < 4; r++) {
        float v = acc[fm][fn][r] + bv;
        if (OUTF32) ((float*)Cout)[(size_t)(row0 + r) * Nout + col] = v;
        else        ((short*)Cout)[(size_t)(row0 + r) * Nout + col] = (short)f2bf(v);
      }
    }
  }
}

// ---------- Flash attention, fragment-ready operands, 2-way KV split ----------
__global__ __launch_bounds__(256, 4) void attn(const short* __restrict__ Qf, const short* __restrict__ Kf,
                                               const short* __restrict__ Vf,
                                               float* __restrict__ Op, float* __restrict__ lp) {
  int bh = blockIdx.x;
  int ch = blockIdx.z;
  int wv = threadIdx.x >> 6, lane = threadIdx.x & 63;
  int c = lane & 31, hi = lane >> 5;
  int q0 = blockIdx.y * 128 + wv * 32;
  const int nkb = N_ / 64;                 // 64 kv-blocks of 32 per chunk
  int kb0 = ch * nkb;                      // starting kv-block index

  // fragment pointers (all lane-coalesced: base + lane*16B)
  const short* Qb = Qf + ((size_t)(bh * 128 + (q0 >> 5)) * 4) * 512 + lane * 8;
  const short* Kb = Kf + ((size_t)(bh * 128 + kb0) * 4) * 512 + lane * 8;
  const short* Vb = Vf + ((size_t)(bh * 128 + kb0) * 4) * 512 + lane * 8;

  short8 qf4[4];
#pragma unroll
  for (int f = 0; f < 4; f++) qf4[f] = *(const short8*)(Qb + f * 512);

  f32x16 o0 = zero16(), o1 = zero16();
  float lsum = 0.f;

  short8 kf[4];
#pragma unroll
  for (int f = 0; f < 4; f++) kf[f] = *(const short8*)(Kb + f * 512);

  for (int it = 0; it < nkb; it++) {
    const short* Vt0 = Vb + (size_t)it * 2048;
    short8 vf00 = *(const short8*)(Vt0);
    short8 vf10 = *(const short8*)(Vt0 + 512);
    short8 vf01 = *(const short8*)(Vt0 + 1024);
    short8 vf11 = *(const short8*)(Vt0 + 1536);

    f32x16 st = zero16();
#pragma unroll
    for (int f = 0; f < 4; f++)
      st = __builtin_amdgcn_mfma_f32_32x32x16_bf16(kf[f], qf4[f], st, 0, 0, 0);

    // prefetch next K tile into regs (wraps on last iter)
    const short* Kn = Kb + (size_t)((it + 1 < nkb) ? it + 1 : 0) * 2048;
    short8 kfn[4];
#pragma unroll
    for (int f = 0; f < 4; f++) kfn[f] = *(const short8*)(Kn + f * 512);

    float ls = 0.f;
    unsigned cpk[8];
#pragma unroll
    for (int q2 = 0; q2 < 4; q2++) {
      float e0 = fexp2(st[4 * q2]),     e1 = fexp2(st[4 * q2 + 1]);
      float e2 = fexp2(st[4 * q2 + 2]), e3 = fexp2(st[4 * q2 + 3]);
      ls += (e0 + e1) + (e2 + e3);
      cpk[2 * q2]     = cvt_pk_bf16(e0, e1);
      cpk[2 * q2 + 1] = cvt_pk_bf16(e2, e3);
    }
    lsum += ls;

    unsigned pc[8];
#pragma unroll
    for (int i = 0; i < 8; i++) pc[i] = (unsigned)__shfl_xor((int)cpk[i], 32);

    union { unsigned u[4]; short8 s; } u0, u1;
    if (hi == 0) {
      u0.u[0] = cpk[0]; u0.u[1] = cpk[1]; u0.u[2] = pc[0]; u0.u[3] = pc[1];
      u1.u[0] = cpk[4]; u1.u[1] = cpk[5]; u1.u[2] = pc[4]; u1.u[3] = pc[5];
    } else {
      u0.u[0] = pc[2]; u0.u[1] = pc[3]; u0.u[2] = cpk[2]; u0.u[3] = cpk[3];
      u1.u[0] = pc[6]; u1.u[1] = pc[7]; u1.u[2] = cpk[6]; u1.u[3] = cpk[7];
    }
    o0 = __builtin_amdgcn_mfma_f32_32x32x16_bf16(u0.s, vf00, o0, 0, 0, 0);
    o0 = __builtin_amdgcn_mfma_f32_32x32x16_bf16(u1.s, vf10, o0, 0, 0, 0);
    o1 = __builtin_amdgcn_mfma_f32_32x32x16_bf16(u0.s, vf01, o1, 0, 0, 0);
    o1 = __builtin_amdgcn_mfma_f32_32x32x16_bf16(u1.s, vf11, o1, 0, 0, 0);

#pragma unroll
    for (int f = 0; f < 4; f++) kf[f] = kfn[f];
  }

  float lt = lsum + __shfl_xor(lsum, 32);
  if (hi == 0) lp[((size_t)ch * 16 + bh) * N_ + q0 + c] = lt;
  float* obase = Op + ((size_t)ch * 16 + bh) * N_ * D_;
#pragma unroll
  for (int r = 0; r < 16; r++) {
    int ql = (r & 3) + 8 * (r >> 2) + 4 * hi;
    int n = q0 + ql;
    obase[(size_t)n * D_ + c]      = o0[r];
    obase[(size_t)n * D_ + 32 + c] = o1[r];
  }
}

// ---------- combine partials -> AO bf16 ----------
__global__ void combine(const float* __restrict__ Op, const float* __restrict__ lp,
                        short* __restrict__ AO) {
  int i = blockIdx.x * blockDim.x + threadIdx.x;   // 16*4096*16
  if (i >= 16 * N_ * 16) return;
  int d4 = i & 15, q = (i >> 4) & (N_ - 1), bh = i >> 16;
  size_t base = ((size_t)bh * N_ + q) * D_ + d4 * 4;
  const size_t chstride = (size_t)16 * N_ * D_;
  float4 a = *(const float4*)(Op + base);
  float4 b = *(const float4*)(Op + base + chstride);
  float l = lp[(size_t)bh * N_ + q] + lp[(size_t)16 * N_ + (size_t)bh * N_ + q];
  float inv = 1.0f / l;
  int bb = bh >> 3, h = bh & 7;
  short4 o;
  o.x = (short)f2bf((a.x + b.x) * inv);
  o.y = (short)f2bf((a.y + b.y) * inv);
  o.z = (short)f2bf((a.z + b.z) * inv);
  o.w = (short)f2bf((a.w + b.w) * inv);
  *(short4*)(AO + ((size_t)(bb * N_ + q)) * C_ + h * D_ + d4 * 4) = o;
}

// ---------- launch ----------
extern "C" void kernel_launch(void* const* d_in, const int* in_sizes, int n_in,
                              void* d_out, int out_size, void* d_ws, size_t ws_size,
                              hipStream_t stream) {
  const float* x     = (const float*)d_in[0];
  const float* Wqkv  = (const float*)d_in[1];
  const float* bqkv  = (const float*)d_in[2];
  const float* Wproj = (const float*)d_in[3];
  const float* bproj = (const float*)d_in[4];
  float* out = (float*)d_out;
  char* ws = (char*)d_ws;

  // persistent region
  const size_t off_wprjb = 0;          // 524,288
  const size_t off_tab   = 524288;     // 1,048,576
  const size_t off_q     = 1572864;    // 8,388,608
  const size_t off_k     = 9961472;    // 8,388,608
  const size_t off_vt    = 18350080;   // 8,388,608
  const size_t off_ao    = 26738688;   // 8,388,608 -> ends 35,127,296
  // phase-1 transient (aliased below by partials)
  const size_t off_xb    = 35127296;   // 8,388,608
  const size_t off_wqkvb = 43515904;   // 1,572,864
  const size_t off_qkvb  = 45088768;   // 25,165,824 -> ends 70,254,592
  // attn-phase partials (alias xb/wqkvb/qkvb)
  const size_t off_op    = 35127296;   // 2*16*4096*64*4 = 33,554,432
  const size_t off_l     = 68681728;   // 2*16*4096*4    =    524,288
  if (ws_size < 70254592) return;

  short* xb    = (short*)(ws + off_xb);
  short* wqkvb = (short*)(ws + off_wqkvb);
  short* wprjb = (short*)(ws + off_wprjb);
  short* qkvb  = (short*)(ws + off_qkvb);
  short* Qfp   = (short*)(ws + off_q);
  short* Kfp   = (short*)(ws + off_k);
  short* Vfp   = (short*)(ws + off_vt);
  short* AOp   = (short*)(ws + off_ao);
  float2* tab  = (float2*)(ws + off_tab);
  float* Opp   = (float*)(ws + off_op);
  float* lpp   = (float*)(ws + off_l);

  cast_f2b<<<dim3(4096), dim3(256), 0, stream>>>(x,     xb,    M_ * C_ / 4);
  cast_f2b<<<dim3(768),  dim3(256), 0, stream>>>(Wqkv,  wqkvb, K3_ * C_ / 4);
  cast_f2b<<<dim3(256),  dim3(256), 0, stream>>>(Wproj, wprjb, C_ * C_ / 4);
  rope_table<<<dim3(512), dim3(256), 0, stream>>>(tab);

  gemm_bt<0><<<dim3(64, 12), dim3(256), 0, stream>>>(xb, wqkvb, bqkv, qkvb, M_, K3_, C_);

  rope_apply<<<dim3(4096), dim3(256), 0, stream>>>(qkvb, tab, Qfp, Kfp);
  vtrans<<<dim3(16, 128), dim3(256), 0, stream>>>(qkvb, Vfp);

  attn<<<dim3(16, 32, 2), dim3(256), 0, stream>>>(Qfp, Kfp, Vfp, Opp, lpp);
  combine<<<dim3(4096), dim3(256), 0, stream>>>(Opp, lpp, AOp);

  gemm_bt<1><<<dim3(64, 4), dim3(256), 0, stream>>>(AOp, wprjb, bproj, (void*)out, M_, C_, C_);
}

// Round 5
// 152.822 us; speedup vs baseline: 1.9930x; 1.0533x over previous
//
#include <hip/hip_runtime.h>
#include <hip/hip_bf16.h>
#include <stdint.h>

#define B_ 2
#define N_ 4096
#define C_ 512
#define H_ 8
#define D_ 64
#define M_ (B_*N_)     // 8192
#define K3_ (3*C_)     // 1536

typedef __attribute__((ext_vector_type(8)))  short short8;
typedef __attribute__((ext_vector_type(4)))  float f32x4;
typedef __attribute__((ext_vector_type(16))) float f32x16;

// ---------- helpers ----------
static __device__ __forceinline__ unsigned short f2bf(float f) {
  union { float f; unsigned u; } cv; cv.f = f;
  unsigned r = cv.u + 0x7fffu + ((cv.u >> 16) & 1u);   // RNE
  return (unsigned short)(r >> 16);
}
static __device__ __forceinline__ float bf2f(short x) {
  union { unsigned u; float f; } cv;
  cv.u = ((unsigned)(unsigned short)x) << 16;
  return cv.f;
}
static __device__ __forceinline__ float fexp2(float x) {
#if __has_builtin(__builtin_amdgcn_exp2f)
  return __builtin_amdgcn_exp2f(x);
#else
  return exp2f(x);
#endif
}
static __device__ __forceinline__ unsigned cvt_pk_bf16(float a, float b) {
  unsigned r;
  asm("v_cvt_pk_bf16_f32 %0, %1, %2" : "=v"(r) : "v"(a), "v"(b));
  return r;   // lo = bf16(a), hi = bf16(b)
}
static __device__ __forceinline__ void gload_lds16(const void* g, void* l) {
  __builtin_amdgcn_global_load_lds((const __attribute__((address_space(1))) unsigned*)g,
                                   (__attribute__((address_space(3))) unsigned*)l, 16, 0, 0);
}
static __device__ __forceinline__ f32x16 zero16() {
  f32x16 z;
#pragma unroll
  for (int i = 0; i < 16; i++) z[i] = 0.f;
  return z;
}

// ---------- f32 -> bf16 cast ----------
__global__ void cast_f2b(const float* __restrict__ in, short* __restrict__ out, int n4) {
  int i = blockIdx.x * blockDim.x + threadIdx.x;
  if (i >= n4) return;
  float4 v = ((const float4*)in)[i];
  short4 o;
  o.x = (short)f2bf(v.x); o.y = (short)f2bf(v.y);
  o.z = (short)f2bf(v.z); o.w = (short)f2bf(v.w);
  ((short4*)out)[i] = o;
}

// ---------- RoPE cos/sin table ----------
__global__ void rope_table(float2* __restrict__ tab) {
  int i = blockIdx.x * blockDim.x + threadIdx.x;   // 4096*32
  if (i >= N_ * 32) return;
  int p = i & 31, n = i >> 5;
  float freq = exp2f(-((float)(2 * p) / 64.0f) * 13.287712379549449f);
  float ang = (float)n * freq;
  float s, c;
  sincosf(ang, &s, &c);
  float2 r; r.x = c; r.y = s;
  tab[i] = r;
}

// ---------- RoPE apply -> fragment-ready Qf/Kf ----------
__global__ void rope_apply(const short* __restrict__ qkvb, const float2* __restrict__ tab,
                           short* __restrict__ Qf, short* __restrict__ Kf) {
  int idx = blockIdx.x * blockDim.x + threadIdx.x;   // 2^20
  if (idx >= 2 * M_ * 64) return;
  int lane  = idx & 63;
  int f     = (idx >> 6) & 3;
  int nblk  = (idx >> 8) & 127;
  int h     = (idx >> 15) & 7;
  int b     = (idx >> 18) & 1;
  int tk    = idx >> 19;               // 0 = q, 1 = k
  int c = lane & 31, hi = lane >> 5;
  int n = nblk * 32 + c;
  int d0 = f * 16 + hi * 8;
  short8 v = *(const short8*)(qkvb + (size_t)(b * N_ + n) * K3_ + tk * C_ + h * D_ + d0);
  const float2* tp = tab + n * 32 + (d0 >> 1);
  float sc = (tk == 0) ? 0.18033688011112042f : 1.0f;  // SCALE * log2(e) on Q
  short8 w;
#pragma unroll
  for (int j = 0; j < 4; j++) {
    float e = bf2f(v[2 * j]), o = bf2f(v[2 * j + 1]);
    float2 cs = tp[j];
    float e2 = (e * cs.x - o * cs.y) * sc;
    float o2 = (e * cs.y + o * cs.x) * sc;
    w[2 * j] = (short)f2bf(e2);
    w[2 * j + 1] = (short)f2bf(o2);
  }
  short* dst = (tk ? Kf : Qf) + (((size_t)((b * H_ + h) * 128 + nblk) * 4 + f) * 512) + lane * 8;
  *(short8*)dst = w;
}

// ---------- V -> fragment-ready Vf ----------
__global__ void vtrans(const short* __restrict__ qkvb, short* __restrict__ Vf) {
  __shared__ short tile[32][72];
  int bh = blockIdx.x;        // 16
  int kblk = blockIdx.y;      // 128
  int b = bh >> 3, h = bh & 7;
  int t = threadIdx.x;
  int n0 = kblk * 32;
  {
    int row = t >> 3, c8 = t & 7;
    short8 v = *(const short8*)(qkvb + (size_t)(b * N_ + n0 + row) * K3_ + 2 * C_ + h * D_ + c8 * 8);
    *(short8*)&tile[row][c8 * 8] = v;
  }
  __syncthreads();
  {
    int frag = t >> 6, lane = t & 63;
    int hi = lane >> 5, c = lane & 31;
    int g = frag & 1, dblk = frag >> 1;
    short8 w;
#pragma unroll
    for (int j = 0; j < 8; j++) w[j] = tile[g * 16 + hi * 8 + j][dblk * 32 + c];
    *(short8*)(Vf + ((size_t)(bh * 128 + kblk) * 4 + frag) * 512 + lane * 8) = w;
  }
}

// ---------- GEMM (m97 structure: global_load_lds width-16 staging) ----------
template<int OUTF32>
__global__ __launch_bounds__(256) void gemm_bt(const short* __restrict__ A, const short* __restrict__ Bw,
                                               const float* __restrict__ bias, void* __restrict__ Cout,
                                               int M, int Nout, int K) {
  __shared__ short As[128 * 32];
  __shared__ short Bs[128 * 32];
  int t = threadIdx.x, lane = t & 63, w = t >> 6, wr = w >> 1, wc = w & 1;
  int tM = blockIdx.x * 128, tN = blockIdx.y * 128;
  int lrow = lane & 15, lhi = lane >> 4;
  f32x4 acc[4][4];
#pragma unroll
  for (int fm = 0; fm < 4; fm++)
#pragma unroll
    for (int fn = 0; fn < 4; fn++)
#pragma unroll
      for (int r = 0; r < 4; r++) acc[fm][fn][r] = 0.f;

  // staging coords: chunk c = p*256 + t -> row = c>>2 (0..127), qword = c&3
  int srow = t >> 2, sq = (t & 3) * 8;
  const short* Ag0 = A  + (size_t)(tM + srow) * K + sq;
  const short* Ag1 = A  + (size_t)(tM + 64 + srow) * K + sq;
  const short* Bg0 = Bw + (size_t)(tN + srow) * K + sq;
  const short* Bg1 = Bw + (size_t)(tN + 64 + srow) * K + sq;
  short* Al0 = As + t * 8;          short* Al1 = As + 2048 + t * 8;
  short* Bl0 = Bs + t * 8;          short* Bl1 = Bs + 2048 + t * 8;

  for (int k0 = 0; k0 < K; k0 += 32) {
    gload_lds16(Ag0 + k0, Al0);
    gload_lds16(Ag1 + k0, Al1);
    gload_lds16(Bg0 + k0, Bl0);
    gload_lds16(Bg1 + k0, Bl1);
    __syncthreads();
    short8 af[4], bfr[4];
#pragma unroll
    for (int f = 0; f < 4; f++) {
      af[f]  = *(const short8*)(As + (wr * 64 + f * 16 + lrow) * 32 + lhi * 8);
      bfr[f] = *(const short8*)(Bs + (wc * 64 + f * 16 + lrow) * 32 + lhi * 8);
    }
#pragma unroll
    for (int fm = 0; fm < 4; fm++)
#pragma unroll
      for (int fn = 0; fn < 4; fn++)
        acc[fm][fn] = __builtin_amdgcn_mfma_f32_16x16x32_bf16(af[fm], bfr[fn], acc[fm][fn], 0, 0, 0);
    __syncthreads();
  }

#pragma unroll
  for (int fn = 0; fn < 4; fn++) {
    int col = tN + wc * 64 + fn * 16 + lrow;
    float bv = bias[col];
#pragma unroll
    for (int fm = 0; fm < 4; fm++) {
      int row0 = tM + wr * 64 + fm * 16 + lhi * 4;
#pragma unroll
      for (int r = 0; r < 4; r++) {
        float v = acc[fm][fn][r] + bv;
        if (OUTF32) ((float*)Cout)[(size_t)(row0 + r) * Nout + col] = v;
        else        ((short*)Cout)[(size_t)(row0 + r) * Nout + col] = (short)f2bf(v);
      }
    }
  }
}

// ---------- Flash attention, fragment-ready operands, 2-way KV split ----------
__global__ __launch_bounds__(256, 4) void attn(const short* __restrict__ Qf, const short* __restrict__ Kf,
                                               const short* __restrict__ Vf,
                                               float* __restrict__ Op, float* __restrict__ lp) {
  int bh = blockIdx.x;
  int ch = blockIdx.z;
  int wv = threadIdx.x >> 6, lane = threadIdx.x & 63;
  int c = lane & 31, hi = lane >> 5;
  int q0 = blockIdx.y * 128 + wv * 32;
  const int nkb = N_ / 64;                 // 64 kv-blocks of 32 per chunk
  int kb0 = ch * nkb;

  const short* Qb = Qf + ((size_t)(bh * 128 + (q0 >> 5)) * 4) * 512 + lane * 8;
  const short* Kb = Kf + ((size_t)(bh * 128 + kb0) * 4) * 512 + lane * 8;
  const short* Vb = Vf + ((size_t)(bh * 128 + kb0) * 4) * 512 + lane * 8;

  short8 qf4[4];
#pragma unroll
  for (int f = 0; f < 4; f++) qf4[f] = *(const short8*)(Qb + f * 512);

  f32x16 o0 = zero16(), o1 = zero16();
  float lsum = 0.f;

  short8 kf[4];
#pragma unroll
  for (int f = 0; f < 4; f++) kf[f] = *(const short8*)(Kb + f * 512);

  for (int it = 0; it < nkb; it++) {
    const short* Vt0 = Vb + (size_t)it * 2048;
    short8 vf00 = *(const short8*)(Vt0);
    short8 vf10 = *(const short8*)(Vt0 + 512);
    short8 vf01 = *(const short8*)(Vt0 + 1024);
    short8 vf11 = *(const short8*)(Vt0 + 1536);

    __builtin_amdgcn_s_setprio(1);
    f32x16 st = zero16();
#pragma unroll
    for (int f = 0; f < 4; f++)
      st = __builtin_amdgcn_mfma_f32_32x32x16_bf16(kf[f], qf4[f], st, 0, 0, 0);
    __builtin_amdgcn_s_setprio(0);

    // prefetch next K tile into regs (wraps on last iter)
    const short* Kn = Kb + (size_t)((it + 1 < nkb) ? it + 1 : 0) * 2048;
    short8 kfn[4];
#pragma unroll
    for (int f = 0; f < 4; f++) kfn[f] = *(const short8*)(Kn + f * 512);

    float ls = 0.f;
    unsigned cpk[8];
#pragma unroll
    for (int q2 = 0; q2 < 4; q2++) {
      float e0 = fexp2(st[4 * q2]),     e1 = fexp2(st[4 * q2 + 1]);
      float e2 = fexp2(st[4 * q2 + 2]), e3 = fexp2(st[4 * q2 + 3]);
      ls += (e0 + e1) + (e2 + e3);
      cpk[2 * q2]     = cvt_pk_bf16(e0, e1);
      cpk[2 * q2 + 1] = cvt_pk_bf16(e2, e3);
    }
    lsum += ls;

    // cross-half exchange: one permlane32_swap yields both [lo|lo] and [hi|hi] words
    unsigned w00 = cpk[0], w02 = cpk[2];
    asm volatile("v_permlane32_swap_b32 %0, %1" : "+v"(w00), "+v"(w02));
    unsigned w01 = cpk[1], w03 = cpk[3];
    asm volatile("v_permlane32_swap_b32 %0, %1" : "+v"(w01), "+v"(w03));
    unsigned w10 = cpk[4], w12 = cpk[6];
    asm volatile("v_permlane32_swap_b32 %0, %1" : "+v"(w10), "+v"(w12));
    unsigned w11 = cpk[5], w13 = cpk[7];
    asm volatile("v_permlane32_swap_b32 %0, %1" : "+v"(w11), "+v"(w13));

    union { unsigned u[4]; short8 s; } u0, u1;
    u0.u[0] = w00; u0.u[1] = w01; u0.u[2] = w02; u0.u[3] = w03;
    u1.u[0] = w10; u1.u[1] = w11; u1.u[2] = w12; u1.u[3] = w13;

    __builtin_amdgcn_s_setprio(1);
    o0 = __builtin_amdgcn_mfma_f32_32x32x16_bf16(u0.s, vf00, o0, 0, 0, 0);
    o0 = __builtin_amdgcn_mfma_f32_32x32x16_bf16(u1.s, vf10, o0, 0, 0, 0);
    o1 = __builtin_amdgcn_mfma_f32_32x32x16_bf16(u0.s, vf01, o1, 0, 0, 0);
    o1 = __builtin_amdgcn_mfma_f32_32x32x16_bf16(u1.s, vf11, o1, 0, 0, 0);
    __builtin_amdgcn_s_setprio(0);

#pragma unroll
    for (int f = 0; f < 4; f++) kf[f] = kfn[f];
  }

  float lt = lsum + __shfl_xor(lsum, 32);
  if (hi == 0) lp[((size_t)ch * 16 + bh) * N_ + q0 + c] = lt;
  float* obase = Op + ((size_t)ch * 16 + bh) * N_ * D_;
#pragma unroll
  for (int r = 0; r < 16; r++) {
    int ql = (r & 3) + 8 * (r >> 2) + 4 * hi;
    int n = q0 + ql;
    obase[(size_t)n * D_ + c]      = o0[r];
    obase[(size_t)n * D_ + 32 + c] = o1[r];
  }
}

// ---------- combine partials -> AO bf16 ----------
__global__ void combine(const float* __restrict__ Op, const float* __restrict__ lp,
                        short* __restrict__ AO) {
  int i = blockIdx.x * blockDim.x + threadIdx.x;   // 16*4096*16
  if (i >= 16 * N_ * 16) return;
  int d4 = i & 15, q = (i >> 4) & (N_ - 1), bh = i >> 16;
  size_t base = ((size_t)bh * N_ + q) * D_ + d4 * 4;
  const size_t chstride = (size_t)16 * N_ * D_;
  float4 a = *(const float4*)(Op + base);
  float4 b = *(const float4*)(Op + base + chstride);
  float l = lp[(size_t)bh * N_ + q] + lp[(size_t)16 * N_ + (size_t)bh * N_ + q];
  float inv = 1.0f / l;
  int bb = bh >> 3, h = bh & 7;
  short4 o;
  o.x = (short)f2bf((a.x + b.x) * inv);
  o.y = (short)f2bf((a.y + b.y) * inv);
  o.z = (short)f2bf((a.z + b.z) * inv);
  o.w = (short)f2bf((a.w + b.w) * inv);
  *(short4*)(AO + ((size_t)(bb * N_ + q)) * C_ + h * D_ + d4 * 4) = o;
}

// ---------- launch ----------
extern "C" void kernel_launch(void* const* d_in, const int* in_sizes, int n_in,
                              void* d_out, int out_size, void* d_ws, size_t ws_size,
                              hipStream_t stream) {
  const float* x     = (const float*)d_in[0];
  const float* Wqkv  = (const float*)d_in[1];
  const float* bqkv  = (const float*)d_in[2];
  const float* Wproj = (const float*)d_in[3];
  const float* bproj = (const float*)d_in[4];
  float* out = (float*)d_out;
  char* ws = (char*)d_ws;

  // persistent region
  const size_t off_wprjb = 0;          // 524,288
  const size_t off_tab   = 524288;     // 1,048,576
  const size_t off_q     = 1572864;    // 8,388,608
  const size_t off_k     = 9961472;    // 8,388,608
  const size_t off_vt    = 18350080;   // 8,388,608
  const size_t off_ao    = 26738688;   // 8,388,608 -> ends 35,127,296
  // phase-1 transient (aliased below by partials)
  const size_t off_xb    = 35127296;   // 8,388,608
  const size_t off_wqkvb = 43515904;   // 1,572,864
  const size_t off_qkvb  = 45088768;   // 25,165,824 -> ends 70,254,592
  // attn-phase partials (alias xb/wqkvb/qkvb)
  const size_t off_op    = 35127296;   // 2*16*4096*64*4 = 33,554,432
  const size_t off_l     = 68681728;   // 2*16*4096*4    =    524,288
  if (ws_size < 70254592) return;

  short* xb    = (short*)(ws + off_xb);
  short* wqkvb = (short*)(ws + off_wqkvb);
  short* wprjb = (short*)(ws + off_wprjb);
  short* qkvb  = (short*)(ws + off_qkvb);
  short* Qfp   = (short*)(ws + off_q);
  short* Kfp   = (short*)(ws + off_k);
  short* Vfp   = (short*)(ws + off_vt);
  short* AOp   = (short*)(ws + off_ao);
  float2* tab  = (float2*)(ws + off_tab);
  float* Opp   = (float*)(ws + off_op);
  float* lpp   = (float*)(ws + off_l);

  cast_f2b<<<dim3(4096), dim3(256), 0, stream>>>(x,     xb,    M_ * C_ / 4);
  cast_f2b<<<dim3(768),  dim3(256), 0, stream>>>(Wqkv,  wqkvb, K3_ * C_ / 4);
  cast_f2b<<<dim3(256),  dim3(256), 0, stream>>>(Wproj, wprjb, C_ * C_ / 4);
  rope_table<<<dim3(512), dim3(256), 0, stream>>>(tab);

  gemm_bt<0><<<dim3(64, 12), dim3(256), 0, stream>>>(xb, wqkvb, bqkv, qkvb, M_, K3_, C_);

  rope_apply<<<dim3(4096), dim3(256), 0, stream>>>(qkvb, tab, Qfp, Kfp);
  vtrans<<<dim3(16, 128), dim3(256), 0, stream>>>(qkvb, Vfp);

  attn<<<dim3(16, 32, 2), dim3(256), 0, stream>>>(Qfp, Kfp, Vfp, Opp, lpp);
  combine<<<dim3(4096), dim3(256), 0, stream>>>(Opp, lpp, AOp);

  gemm_bt<1><<<dim3(64, 4), dim3(256), 0, stream>>>(AOp, wprjb, bproj, (void*)out, M_, C_, C_);
}